// Round 5
// baseline (565.350 us; speedup 1.0000x reference)
//
#include <hip/hip_runtime.h>
#include <cmath>

namespace {

typedef _Float16 h8 __attribute__((ext_vector_type(8)));

constexpr int C_     = 64;
constexpr int L_     = 32768;
constexpr int TILE   = 4096;
constexpr int HALO   = 776;           // receptive field 765, rounded to unit-8
constexpr int NB     = TILE + HALO;   // 4872 halfs
constexpr int NU     = NB / 8;        // 609 h8 units
constexpr int HALO_U = HALO / 8;      // 97
constexpr int NT     = L_ / TILE;     // 8 tiles per row
constexpr int BLK    = 256;
constexpr int S2N    = NU - 2 * BLK;  // 97: threads with a third unit

__device__ __forceinline__ h8 ld8(const _Float16* p) { return *reinterpret_cast<const h8*>(p); }
__device__ __forceinline__ void st8(_Float16* p, h8 v) { *reinterpret_cast<h8*>(p) = v; }
__device__ __forceinline__ float4 ld4f(const float* p) { return *reinterpret_cast<const float4*>(p); }
__device__ __forceinline__ void st4f(float* p, float4 v) { *reinterpret_cast<float4*>(p) = v; }
__device__ __forceinline__ h8 sp8(_Float16 v) { return (h8){v,v,v,v,v,v,v,v}; }

template<int K>
__device__ __forceinline__ h8 shconc(h8 A, h8 B) {
    return __builtin_shufflevector(A, B, K, K+1, K+2, K+3, K+4, K+5, K+6, K+7);
}

// tanh-form GELU: v * sigmoid(1.5958*v + 0.07135*v^3); measured absmax-neutral
__device__ __forceinline__ float gelu_f(float v) {
    const float z = v * (1.5957691216057308f + 0.0713548162726f * v * v);
    const float e = __expf(-z);
    return v * __builtin_amdgcn_rcpf(1.0f + e);
}

// One unit (8 elems) of one level. T3 = own running low (registers);
// T0..T2 from LDS at unit offsets. CLAMP (slot 0 only): clamp tap indices at 0
// — garbage below the valid frontier is never read by valid units (frontier
// recursion: starts 1,2,4,7,13,25,49,97 units; level-D valid unit g reads
// g-3D/8 >= prev start). Tile 0 stages true zeros, so its values are exact.
template<int D, bool CLAMP, bool LAST>
__device__ __forceinline__ void unit_step(const _Float16* __restrict__ src,
                                          int g, h8& lwv, h8& yv, bool doY,
                                          const _Float16* c1, const _Float16* c0)
{
    const h8 T3 = lwv;
    h8 T0, T1, T2;
    if constexpr (D == 1) {            // taps at -3,-2,-1 halfs
        int gl = g - 1; if constexpr (CLAMP) gl = gl < 0 ? 0 : gl;
        const h8 Lv = ld8(&src[8 * gl]);
        T0 = shconc<5>(Lv, T3); T1 = shconc<6>(Lv, T3); T2 = shconc<7>(Lv, T3);
    } else if constexpr (D == 2) {     // -6,-4,-2 halfs
        int gl = g - 1; if constexpr (CLAMP) gl = gl < 0 ? 0 : gl;
        const h8 Lv = ld8(&src[8 * gl]);
        T0 = shconc<2>(Lv, T3); T1 = shconc<4>(Lv, T3); T2 = shconc<6>(Lv, T3);
    } else if constexpr (D == 4) {     // -12,-8,-4 halfs
        int g1 = g - 1, g2 = g - 2;
        if constexpr (CLAMP) { g1 = g1 < 0 ? 0 : g1; g2 = g2 < 0 ? 0 : g2; }
        const h8 Lv = ld8(&src[8 * g1]);
        const h8 LL = ld8(&src[8 * g2]);
        T0 = shconc<4>(LL, Lv); T1 = Lv; T2 = shconc<4>(Lv, T3);
    } else {                           // unit-aligned taps
        constexpr int UD = D / 8;
        int g1 = g - UD, g2 = g - 2 * UD, g3 = g - 3 * UD;
        if constexpr (CLAMP) {
            g1 = g1 < 0 ? 0 : g1; g2 = g2 < 0 ? 0 : g2; g3 = g3 < 0 ? 0 : g3;
        }
        T0 = ld8(&src[8 * g3]); T1 = ld8(&src[8 * g2]); T2 = ld8(&src[8 * g1]);
    }
    if (doY)
        yv += sp8(c1[0])*T0 + sp8(c1[1])*T1 + sp8(c1[2])*T2 + sp8(c1[3])*T3;
    const h8 nl = sp8(c0[0])*T0 + sp8(c0[1])*T1 + sp8(c0[2])*T2 + sp8(c0[3])*T3;
    if constexpr (LAST) yv += nl;      // c0 pre-folded with w0
    else lwv = nl;
}

template<int D, bool LAST>
__device__ __forceinline__ void level(const _Float16* __restrict__ src,
                                      _Float16* __restrict__ dst,
                                      h8* lw, h8* yacc,
                                      const float* h0v, const float* h1v,
                                      float wi, float w0,
                                      int tid, bool y0, bool s2)
{
    _Float16 c1[4], c0[4];
#pragma unroll
    for (int t = 0; t < 4; ++t) {
        c1[t] = (_Float16)(wi * h1v[t]);
        c0[t] = (_Float16)(LAST ? w0 * h0v[t] : h0v[t]);
    }
    unit_step<D, true,  LAST>(src, tid,           lw[0], yacc[0], y0,   c1, c0);
    unit_step<D, false, LAST>(src, tid + BLK,     lw[1], yacc[1], true, c1, c0);
    if (s2)
        unit_step<D, false, LAST>(src, tid + 2*BLK, lw[2], yacc[2], true, c1, c0);
    if constexpr (!LAST) {
        st8(&dst[8 * tid],           lw[0]);
        st8(&dst[8 * (tid + BLK)],   lw[1]);
        if (s2) st8(&dst[8 * (tid + 2*BLK)], lw[2]);
    }
}

__global__ __launch_bounds__(BLK, 8)
void cmrc_kernel(const float* __restrict__ x,
                 const float* __restrict__ h0,
                 const float* __restrict__ h1,
                 const float* __restrict__ w,
                 float* __restrict__ out)
{
    __shared__ alignas(16) _Float16 buf[2][NB];

    const int tid  = threadIdx.x;
    const int blk  = blockIdx.x;
    const int tile = blk % NT;
    const int bc   = blk / NT;            // b*C + c
    const int c    = bc % C_;
    const long row = (long)bc * L_;
    const int  t0  = tile * TILE - HALO;  // global pos of buffer p=0

    float h0v[4], h1v[4];
#pragma unroll
    for (int k = 0; k < 4; ++k) { h0v[k] = h0[c*4+k]; h1v[k] = h1[c*4+k]; }
    float wv[10];
#pragma unroll
    for (int i = 0; i < 10; ++i) wv[i] = w[c*10+i];

    const bool y0 = (tid >= HALO_U);   // slot-0 unit is inside the output tile
    const bool s2 = (tid < S2N);       // this thread owns a third unit

    h8 lw[3];    // running low residual (own units)
    h8 yacc[3];  // packed y accumulator

    const _Float16 w9h = (_Float16)wv[9];

    // Stage x as fp16 (coalesced; zeros left of t=0); init lw = x, y = w9*x.
#pragma unroll
    for (int j = 0; j < 3; ++j) {
        yacc[j] = sp8((_Float16)0.f);
        const int un = tid + j * BLK;
        if (j < 2 || s2) {
            const int p = 8 * un;
            const int t = t0 + p;
            float4 xa = make_float4(0.f,0.f,0.f,0.f);
            float4 xb = make_float4(0.f,0.f,0.f,0.f);
            if (t >= 0)     xa = ld4f(&x[row + t]);
            if (t + 4 >= 0) xb = ld4f(&x[row + t + 4]);
            h8 hv;
            hv[0]=(_Float16)xa.x; hv[1]=(_Float16)xa.y; hv[2]=(_Float16)xa.z; hv[3]=(_Float16)xa.w;
            hv[4]=(_Float16)xb.x; hv[5]=(_Float16)xb.y; hv[6]=(_Float16)xb.z; hv[7]=(_Float16)xb.w;
            st8(&buf[0][p], hv);
            lw[j] = hv;
            if (j > 0 || y0) yacc[j] = sp8(w9h) * hv;
        }
    }
    __syncthreads();

    level<1,   false>(buf[0], buf[1], lw, yacc, h0v, h1v, wv[8], 0.f, tid, y0, s2); __syncthreads();
    level<2,   false>(buf[1], buf[0], lw, yacc, h0v, h1v, wv[7], 0.f, tid, y0, s2); __syncthreads();
    level<4,   false>(buf[0], buf[1], lw, yacc, h0v, h1v, wv[6], 0.f, tid, y0, s2); __syncthreads();
    level<8,   false>(buf[1], buf[0], lw, yacc, h0v, h1v, wv[5], 0.f, tid, y0, s2); __syncthreads();
    level<16,  false>(buf[0], buf[1], lw, yacc, h0v, h1v, wv[4], 0.f, tid, y0, s2); __syncthreads();
    level<32,  false>(buf[1], buf[0], lw, yacc, h0v, h1v, wv[3], 0.f, tid, y0, s2); __syncthreads();
    level<64,  false>(buf[0], buf[1], lw, yacc, h0v, h1v, wv[2], 0.f, tid, y0, s2); __syncthreads();
    level<128, true >(buf[1], buf[0], lw, yacc, h0v, h1v, wv[1], wv[0], tid, y0, s2);

    // Epilogue: fp32 GELU, two float4 stores per unit.
    auto emit = [&](int g, h8 v) {
        float4 oa, ob;
        oa.x = gelu_f((float)v[0]); oa.y = gelu_f((float)v[1]);
        oa.z = gelu_f((float)v[2]); oa.w = gelu_f((float)v[3]);
        ob.x = gelu_f((float)v[4]); ob.y = gelu_f((float)v[5]);
        ob.z = gelu_f((float)v[6]); ob.w = gelu_f((float)v[7]);
        const long idx = row + (t0 + 8 * g);
        st4f(&out[idx], oa);
        st4f(&out[idx + 4], ob);
    };
    if (y0) emit(tid,           yacc[0]);
    emit(tid + BLK,             yacc[1]);
    if (s2) emit(tid + 2 * BLK, yacc[2]);
}

}  // namespace

extern "C" void kernel_launch(void* const* d_in, const int* in_sizes, int n_in,
                              void* d_out, int out_size, void* d_ws, size_t ws_size,
                              hipStream_t stream)
{
    const float* x  = (const float*)d_in[0];
    const float* h0 = (const float*)d_in[1];
    const float* h1 = (const float*)d_in[2];
    const float* w  = (const float*)d_in[3];
    float* out = (float*)d_out;

    const int nblocks = (out_size / L_) * NT;   // B*C*NT = 4096
    cmrc_kernel<<<nblocks, BLK, 0, stream>>>(x, h0, h1, w, out);
}

// Round 6
// 453.973 us; speedup vs baseline: 1.2453x; 1.2453x over previous
//
#include <hip/hip_runtime.h>
#include <cmath>

namespace {

typedef _Float16 h8 __attribute__((ext_vector_type(8)));

constexpr int C_     = 64;
constexpr int L_     = 32768;
constexpr int TILE   = 4096;
constexpr int HALO   = 776;           // receptive field 765, rounded to unit-8
constexpr int NB     = TILE + HALO;   // 4872 halfs live
constexpr int NU     = NB / 8;        // 609 real h8 units
constexpr int HALO_U = HALO / 8;      // 97
constexpr int NT     = L_ / TILE;     // 8 tiles per row
constexpr int BLK    = 256;
constexpr int NUP    = 3 * BLK;       // 768 padded units (609..767 = dump zone)

__device__ __forceinline__ h8 ld8(const _Float16* p) { return *reinterpret_cast<const h8*>(p); }
__device__ __forceinline__ void st8(_Float16* p, h8 v) { *reinterpret_cast<h8*>(p) = v; }
__device__ __forceinline__ float4 ld4f(const float* p) { return *reinterpret_cast<const float4*>(p); }
__device__ __forceinline__ void st4f(float* p, float4 v) { *reinterpret_cast<float4*>(p) = v; }
__device__ __forceinline__ h8 sp8(_Float16 v) { return (h8){v,v,v,v,v,v,v,v}; }

template<int K>
__device__ __forceinline__ h8 shconc(h8 A, h8 B) {
    return __builtin_shufflevector(A, B, K, K+1, K+2, K+3, K+4, K+5, K+6, K+7);
}

// tanh-form GELU: v * sigmoid(1.5958*v + 0.07135*v^3); absmax-verified vs erf
__device__ __forceinline__ float gelu_f(float v) {
    const float z = v * (1.5957691216057308f + 0.0713548162726f * v * v);
    const float e = __expf(-z);
    return v * __builtin_amdgcn_rcpf(1.0f + e);
}

// One unit (8 elems) of one level, fully unconditional. T3 = own running low
// (registers); T0..T2 from LDS. CLAMP (slot 0 only) clamps tap unit-indices at
// 0 for memory safety; below-frontier garbage is never read by valid units
// (frontier starts 1,2,4,7,13,25,49,97 units; level-D valid unit g reads
// g-3D/8 >= prev start — verified logic, r5 passed correctness with it).
// y-accum runs unguarded: garbage y is never stored.
template<int D, bool CLAMP, bool LAST>
__device__ __forceinline__ void unit_step(const _Float16* __restrict__ src,
                                          int g, h8& lwv, h8& yv,
                                          const _Float16* c1, const _Float16* c0)
{
    const h8 T3 = lwv;
    h8 T0, T1, T2;
    if constexpr (D == 1) {            // taps at -3,-2,-1 halfs
        int gl = g - 1; if constexpr (CLAMP) gl = gl < 0 ? 0 : gl;
        const h8 Lv = ld8(&src[8 * gl]);
        T0 = shconc<5>(Lv, T3); T1 = shconc<6>(Lv, T3); T2 = shconc<7>(Lv, T3);
    } else if constexpr (D == 2) {     // -6,-4,-2 halfs
        int gl = g - 1; if constexpr (CLAMP) gl = gl < 0 ? 0 : gl;
        const h8 Lv = ld8(&src[8 * gl]);
        T0 = shconc<2>(Lv, T3); T1 = shconc<4>(Lv, T3); T2 = shconc<6>(Lv, T3);
    } else if constexpr (D == 4) {     // -12,-8,-4 halfs
        int g1 = g - 1, g2 = g - 2;
        if constexpr (CLAMP) { g1 = g1 < 0 ? 0 : g1; g2 = g2 < 0 ? 0 : g2; }
        const h8 Lv = ld8(&src[8 * g1]);
        const h8 LL = ld8(&src[8 * g2]);
        T0 = shconc<4>(LL, Lv); T1 = Lv; T2 = shconc<4>(Lv, T3);
    } else {                           // unit-aligned taps
        constexpr int UD = D / 8;
        int g1 = g - UD, g2 = g - 2 * UD, g3 = g - 3 * UD;
        if constexpr (CLAMP) {
            g1 = g1 < 0 ? 0 : g1; g2 = g2 < 0 ? 0 : g2; g3 = g3 < 0 ? 0 : g3;
        }
        T0 = ld8(&src[8 * g3]); T1 = ld8(&src[8 * g2]); T2 = ld8(&src[8 * g1]);
    }
    yv += sp8(c1[0])*T0 + sp8(c1[1])*T1 + sp8(c1[2])*T2 + sp8(c1[3])*T3;
    const h8 nl = sp8(c0[0])*T0 + sp8(c0[1])*T1 + sp8(c0[2])*T2 + sp8(c0[3])*T3;
    if constexpr (LAST) yv += nl;      // c0 pre-folded with w0
    else lwv = nl;
}

template<int D, bool LAST>
__device__ __forceinline__ void level(const _Float16* __restrict__ src,
                                      _Float16* __restrict__ dst,
                                      h8& lw0, h8& lw1, h8& lw2,
                                      h8& ya0, h8& ya1, h8& ya2,
                                      const float* h0v, const float* h1v,
                                      float wi, float w0, int tid)
{
    _Float16 c1[4], c0[4];
#pragma unroll
    for (int t = 0; t < 4; ++t) {
        c1[t] = (_Float16)(wi * h1v[t]);
        c0[t] = (_Float16)(LAST ? w0 * h0v[t] : h0v[t]);
    }
    unit_step<D, true,  LAST>(src, tid,           lw0, ya0, c1, c0);
    unit_step<D, false, LAST>(src, tid + BLK,     lw1, ya1, c1, c0);
    unit_step<D, false, LAST>(src, tid + 2*BLK,   lw2, ya2, c1, c0);
    if constexpr (!LAST) {
        st8(&dst[8 * tid],             lw0);
        st8(&dst[8 * (tid + BLK)],     lw1);
        st8(&dst[8 * (tid + 2*BLK)],   lw2);
    }
}

__global__ __launch_bounds__(BLK, 5)
void cmrc_kernel(const float* __restrict__ x,
                 const float* __restrict__ h0,
                 const float* __restrict__ h1,
                 const float* __restrict__ w,
                 float* __restrict__ out)
{
    __shared__ alignas(16) _Float16 buf[2][NUP * 8];   // 24576 B total

    const int tid  = threadIdx.x;
    const int blk  = blockIdx.x;
    const int tile = blk % NT;
    const int bc   = blk / NT;            // b*C + c
    const int c    = bc % C_;
    const long row = (long)bc * L_;
    const int  t0  = tile * TILE - HALO;  // global pos of buffer p=0

    float h0v[4], h1v[4];
#pragma unroll
    for (int k = 0; k < 4; ++k) { h0v[k] = h0[c*4+k]; h1v[k] = h1[c*4+k]; }
    float wv[10];
#pragma unroll
    for (int i = 0; i < 10; ++i) wv[i] = w[c*10+i];

    h8 lw0, lw1, lw2;    // running low residual (own units)
    h8 ya0, ya1, ya2;    // packed y accumulators

    const _Float16 w9h = (_Float16)wv[9];

    // ---- Stage x as fp16; init lw = x, y = w9*x ----
    // Slots 0,1 (units tid, tid+256): zero-fill left of t=0 (t is a multiple
    // of 8, so one guard covers both float4 halves).
    {
        const int t = t0 + 8 * tid;
        float4 xa = make_float4(0.f,0.f,0.f,0.f), xb = xa;
        if (t >= 0) { xa = ld4f(&x[row + t]); xb = ld4f(&x[row + t + 4]); }
        h8 hv;
        hv[0]=(_Float16)xa.x; hv[1]=(_Float16)xa.y; hv[2]=(_Float16)xa.z; hv[3]=(_Float16)xa.w;
        hv[4]=(_Float16)xb.x; hv[5]=(_Float16)xb.y; hv[6]=(_Float16)xb.z; hv[7]=(_Float16)xb.w;
        st8(&buf[0][8 * tid], hv);
        lw0 = hv; ya0 = sp8(w9h) * hv;
    }
    {
        const int t = t0 + 8 * (tid + BLK);
        float4 xa = make_float4(0.f,0.f,0.f,0.f), xb = xa;
        if (t >= 0) { xa = ld4f(&x[row + t]); xb = ld4f(&x[row + t + 4]); }
        h8 hv;
        hv[0]=(_Float16)xa.x; hv[1]=(_Float16)xa.y; hv[2]=(_Float16)xa.z; hv[3]=(_Float16)xa.w;
        hv[4]=(_Float16)xb.x; hv[5]=(_Float16)xb.y; hv[6]=(_Float16)xb.z; hv[7]=(_Float16)xb.w;
        st8(&buf[0][8 * (tid + BLK)], hv);
        lw1 = hv; ya1 = sp8(w9h) * hv;
    }
    // Slot 2 (units tid+512, incl. dump zone 609..767): clamp the high side;
    // t >= 512*8-776 > 0 always. Garbage values for dump units never escape.
    {
        int t = t0 + 8 * (tid + 2 * BLK);
        t = t > (L_ - 8) ? (L_ - 8) : t;
        const float4 xa = ld4f(&x[row + t]);
        const float4 xb = ld4f(&x[row + t + 4]);
        h8 hv;
        hv[0]=(_Float16)xa.x; hv[1]=(_Float16)xa.y; hv[2]=(_Float16)xa.z; hv[3]=(_Float16)xa.w;
        hv[4]=(_Float16)xb.x; hv[5]=(_Float16)xb.y; hv[6]=(_Float16)xb.z; hv[7]=(_Float16)xb.w;
        st8(&buf[0][8 * (tid + 2 * BLK)], hv);
        lw2 = hv; ya2 = sp8(w9h) * hv;
    }
    __syncthreads();

    level<1,   false>(buf[0], buf[1], lw0,lw1,lw2, ya0,ya1,ya2, h0v,h1v, wv[8], 0.f, tid); __syncthreads();
    level<2,   false>(buf[1], buf[0], lw0,lw1,lw2, ya0,ya1,ya2, h0v,h1v, wv[7], 0.f, tid); __syncthreads();
    level<4,   false>(buf[0], buf[1], lw0,lw1,lw2, ya0,ya1,ya2, h0v,h1v, wv[6], 0.f, tid); __syncthreads();
    level<8,   false>(buf[1], buf[0], lw0,lw1,lw2, ya0,ya1,ya2, h0v,h1v, wv[5], 0.f, tid); __syncthreads();
    level<16,  false>(buf[0], buf[1], lw0,lw1,lw2, ya0,ya1,ya2, h0v,h1v, wv[4], 0.f, tid); __syncthreads();
    level<32,  false>(buf[1], buf[0], lw0,lw1,lw2, ya0,ya1,ya2, h0v,h1v, wv[3], 0.f, tid); __syncthreads();
    level<64,  false>(buf[0], buf[1], lw0,lw1,lw2, ya0,ya1,ya2, h0v,h1v, wv[2], 0.f, tid); __syncthreads();
    level<128, true >(buf[1], buf[0], lw0,lw1,lw2, ya0,ya1,ya2, h0v,h1v, wv[1], wv[0], tid);

    // ---- Epilogue: fp32 GELU, two float4 stores per stored unit ----
    auto emit = [&](int g, h8 v) {
        float4 oa, ob;
        oa.x = gelu_f((float)v[0]); oa.y = gelu_f((float)v[1]);
        oa.z = gelu_f((float)v[2]); oa.w = gelu_f((float)v[3]);
        ob.x = gelu_f((float)v[4]); ob.y = gelu_f((float)v[5]);
        ob.z = gelu_f((float)v[6]); ob.w = gelu_f((float)v[7]);
        const long idx = row + (t0 + 8 * g);
        st4f(&out[idx], oa);
        st4f(&out[idx + 4], ob);
    };
    if (tid >= HALO_U) emit(tid,       ya0);   // slot0 in-tile part
    emit(tid + BLK,                    ya1);   // slot1 always in-tile
    if (tid < NU - 2 * BLK) emit(tid + 2 * BLK, ya2);   // real slot2 units only
}

}  // namespace

extern "C" void kernel_launch(void* const* d_in, const int* in_sizes, int n_in,
                              void* d_out, int out_size, void* d_ws, size_t ws_size,
                              hipStream_t stream)
{
    const float* x  = (const float*)d_in[0];
    const float* h0 = (const float*)d_in[1];
    const float* h1 = (const float*)d_in[2];
    const float* w  = (const float*)d_in[3];
    float* out = (float*)d_out;

    const int nblocks = (out_size / L_) * NT;   // B*C*NT = 4096
    cmrc_kernel<<<nblocks, BLK, 0, stream>>>(x, h0, h1, w, out);
}

// Round 7
// 90.356 us; speedup vs baseline: 6.2569x; 5.0243x over previous
//
#include <hip/hip_runtime.h>
#include <cmath>

namespace {

typedef _Float16 h8 __attribute__((ext_vector_type(8)));

constexpr int C_     = 64;
constexpr int L_     = 32768;
constexpr int TILE   = 4096;
constexpr int HALO   = 776;           // receptive field 765, rounded to unit-8
constexpr int NB     = TILE + HALO;   // 4872 halfs live
constexpr int NU     = NB / 8;        // 609 real h8 units
constexpr int HALO_U = HALO / 8;      // 97
constexpr int NT     = L_ / TILE;     // 8 tiles per row
constexpr int BLK    = 256;
constexpr int NUP    = 3 * BLK;       // 768 padded units (609..767 = dump zone)

__device__ __forceinline__ h8 ld8(const _Float16* p) { return *reinterpret_cast<const h8*>(p); }
__device__ __forceinline__ void st8(_Float16* p, h8 v) { *reinterpret_cast<h8*>(p) = v; }
__device__ __forceinline__ float4 ld4f(const float* p) { return *reinterpret_cast<const float4*>(p); }
__device__ __forceinline__ void st4f(float* p, float4 v) { *reinterpret_cast<float4*>(p) = v; }
__device__ __forceinline__ h8 sp8(_Float16 v) { return (h8){v,v,v,v,v,v,v,v}; }

template<int K>
__device__ __forceinline__ h8 shconc(h8 A, h8 B) {
    return __builtin_shufflevector(A, B, K, K+1, K+2, K+3, K+4, K+5, K+6, K+7);
}

// tanh-form GELU: v * sigmoid(1.5958*v + 0.07135*v^3); absmax-verified vs erf
// (r4/r5/r6 all 0.0078125, identical to the erf version in r3).
__device__ __forceinline__ float gelu_f(float v) {
    const float z = v * (1.5957691216057308f + 0.0713548162726f * v * v);
    const float e = __expf(-z);
    return v * __builtin_amdgcn_rcpf(1.0f + e);
}

// One unit (8 elems) of one level, fully unconditional. T3 = own running low
// (registers); T0..T2 from LDS. CLAMP (slot 0 only) clamps tap unit-indices at
// 0 for memory safety; below-frontier garbage is never read by valid units
// (frontier starts 1,2,4,7,13,25,49,97 units; level-D valid unit g reads
// g-3D/8 >= prev start — correctness-verified in r5/r6 runs).
// y-accum runs unguarded: garbage y is never stored.
template<int D, bool CLAMP, bool LAST>
__device__ __forceinline__ void unit_step(const _Float16* __restrict__ src,
                                          int g, h8& lwv, h8& yv,
                                          const _Float16* c1, const _Float16* c0)
{
    const h8 T3 = lwv;
    h8 T0, T1, T2;
    if constexpr (D == 1) {            // taps at -3,-2,-1 halfs
        int gl = g - 1; if constexpr (CLAMP) gl = gl < 0 ? 0 : gl;
        const h8 Lv = ld8(&src[8 * gl]);
        T0 = shconc<5>(Lv, T3); T1 = shconc<6>(Lv, T3); T2 = shconc<7>(Lv, T3);
    } else if constexpr (D == 2) {     // -6,-4,-2 halfs
        int gl = g - 1; if constexpr (CLAMP) gl = gl < 0 ? 0 : gl;
        const h8 Lv = ld8(&src[8 * gl]);
        T0 = shconc<2>(Lv, T3); T1 = shconc<4>(Lv, T3); T2 = shconc<6>(Lv, T3);
    } else if constexpr (D == 4) {     // -12,-8,-4 halfs
        int g1 = g - 1, g2 = g - 2;
        if constexpr (CLAMP) { g1 = g1 < 0 ? 0 : g1; g2 = g2 < 0 ? 0 : g2; }
        const h8 Lv = ld8(&src[8 * g1]);
        const h8 LL = ld8(&src[8 * g2]);
        T0 = shconc<4>(LL, Lv); T1 = Lv; T2 = shconc<4>(Lv, T3);
    } else {                           // unit-aligned taps
        constexpr int UD = D / 8;
        int g1 = g - UD, g2 = g - 2 * UD, g3 = g - 3 * UD;
        if constexpr (CLAMP) {
            g1 = g1 < 0 ? 0 : g1; g2 = g2 < 0 ? 0 : g2; g3 = g3 < 0 ? 0 : g3;
        }
        T0 = ld8(&src[8 * g3]); T1 = ld8(&src[8 * g2]); T2 = ld8(&src[8 * g1]);
    }
    yv += sp8(c1[0])*T0 + sp8(c1[1])*T1 + sp8(c1[2])*T2 + sp8(c1[3])*T3;
    const h8 nl = sp8(c0[0])*T0 + sp8(c0[1])*T1 + sp8(c0[2])*T2 + sp8(c0[3])*T3;
    if constexpr (LAST) yv += nl;      // c0 pre-folded with w0
    else lwv = nl;
}

template<int D, bool LAST>
__device__ __forceinline__ void level(const _Float16* __restrict__ src,
                                      _Float16* __restrict__ dst,
                                      h8& lw0, h8& lw1, h8& lw2,
                                      h8& ya0, h8& ya1, h8& ya2,
                                      const float* h0v, const float* h1v,
                                      float wi, float w0, int tid)
{
    _Float16 c1[4], c0[4];
#pragma unroll
    for (int t = 0; t < 4; ++t) {
        c1[t] = (_Float16)(wi * h1v[t]);
        c0[t] = (_Float16)(LAST ? w0 * h0v[t] : h0v[t]);
    }
    unit_step<D, true,  LAST>(src, tid,           lw0, ya0, c1, c0);
    unit_step<D, false, LAST>(src, tid + BLK,     lw1, ya1, c1, c0);
    unit_step<D, false, LAST>(src, tid + 2*BLK,   lw2, ya2, c1, c0);
    if constexpr (!LAST) {
        st8(&dst[8 * tid],             lw0);
        st8(&dst[8 * (tid + BLK)],     lw1);
        st8(&dst[8 * (tid + 2*BLK)],   lw2);
    }
}

// NO min-waves arg: caps below the hoisted live pressure (~80-100 VGPR)
// forced wholesale scratch demotion in r4/r5/r6 (WRITE_SIZE 0.26-1.3 GB,
// 2-12x slowdown). Capless: compiler allocates true pressure, HW picks
// occupancy from the VGPR table (<=102 -> 5 waves/SIMD, <=128 -> 4).
__global__ __launch_bounds__(BLK)
void cmrc_kernel(const float* __restrict__ x,
                 const float* __restrict__ h0,
                 const float* __restrict__ h1,
                 const float* __restrict__ w,
                 float* __restrict__ out)
{
    __shared__ alignas(16) _Float16 buf[2][NUP * 8];   // 24576 B total

    const int tid  = threadIdx.x;
    const int blk  = blockIdx.x;
    const int tile = blk % NT;
    const int bc   = blk / NT;            // b*C + c
    const int c    = bc % C_;
    const long row = (long)bc * L_;
    const int  t0  = tile * TILE - HALO;  // global pos of buffer p=0

    float h0v[4], h1v[4];
#pragma unroll
    for (int k = 0; k < 4; ++k) { h0v[k] = h0[c*4+k]; h1v[k] = h1[c*4+k]; }
    float wv[10];
#pragma unroll
    for (int i = 0; i < 10; ++i) wv[i] = w[c*10+i];

    h8 lw0, lw1, lw2;    // running low residual (own units)
    h8 ya0, ya1, ya2;    // packed y accumulators

    const _Float16 w9h = (_Float16)wv[9];

    // ---- Stage x as fp16; init lw = x, y = w9*x ----
    // Slot 0 (units 0..255): left-guard (t<0 only possible here, tile 0).
    {
        const int t = t0 + 8 * tid;
        float4 xa = make_float4(0.f,0.f,0.f,0.f), xb = xa;
        if (t >= 0) { xa = ld4f(&x[row + t]); xb = ld4f(&x[row + t + 4]); }
        h8 hv;
        hv[0]=(_Float16)xa.x; hv[1]=(_Float16)xa.y; hv[2]=(_Float16)xa.z; hv[3]=(_Float16)xa.w;
        hv[4]=(_Float16)xb.x; hv[5]=(_Float16)xb.y; hv[6]=(_Float16)xb.z; hv[7]=(_Float16)xb.w;
        st8(&buf[0][8 * tid], hv);
        lw0 = hv; ya0 = sp8(w9h) * hv;
    }
    // Slot 1 (units 256..511): t >= 256*8-776 = 1272 > 0 and
    // t+7 <= t0+4095 < L always -> unconditional.
    {
        const int t = t0 + 8 * (tid + BLK);
        const float4 xa = ld4f(&x[row + t]);
        const float4 xb = ld4f(&x[row + t + 4]);
        h8 hv;
        hv[0]=(_Float16)xa.x; hv[1]=(_Float16)xa.y; hv[2]=(_Float16)xa.z; hv[3]=(_Float16)xa.w;
        hv[4]=(_Float16)xb.x; hv[5]=(_Float16)xb.y; hv[6]=(_Float16)xb.z; hv[7]=(_Float16)xb.w;
        st8(&buf[0][8 * (tid + BLK)], hv);
        lw1 = hv; ya1 = sp8(w9h) * hv;
    }
    // Slot 2 (units 512..767, incl. dump zone 609..767): clamp the high side;
    // t >= 512*8-776 > 0 always. Dump-zone garbage never escapes (taps only
    // reach downward; epilogue guards the store).
    {
        int t = t0 + 8 * (tid + 2 * BLK);
        t = t > (L_ - 8) ? (L_ - 8) : t;
        const float4 xa = ld4f(&x[row + t]);
        const float4 xb = ld4f(&x[row + t + 4]);
        h8 hv;
        hv[0]=(_Float16)xa.x; hv[1]=(_Float16)xa.y; hv[2]=(_Float16)xa.z; hv[3]=(_Float16)xa.w;
        hv[4]=(_Float16)xb.x; hv[5]=(_Float16)xb.y; hv[6]=(_Float16)xb.z; hv[7]=(_Float16)xb.w;
        st8(&buf[0][8 * (tid + 2 * BLK)], hv);
        lw2 = hv; ya2 = sp8(w9h) * hv;
    }
    __syncthreads();

    level<1,   false>(buf[0], buf[1], lw0,lw1,lw2, ya0,ya1,ya2, h0v,h1v, wv[8], 0.f, tid); __syncthreads();
    level<2,   false>(buf[1], buf[0], lw0,lw1,lw2, ya0,ya1,ya2, h0v,h1v, wv[7], 0.f, tid); __syncthreads();
    level<4,   false>(buf[0], buf[1], lw0,lw1,lw2, ya0,ya1,ya2, h0v,h1v, wv[6], 0.f, tid); __syncthreads();
    level<8,   false>(buf[1], buf[0], lw0,lw1,lw2, ya0,ya1,ya2, h0v,h1v, wv[5], 0.f, tid); __syncthreads();
    level<16,  false>(buf[0], buf[1], lw0,lw1,lw2, ya0,ya1,ya2, h0v,h1v, wv[4], 0.f, tid); __syncthreads();
    level<32,  false>(buf[1], buf[0], lw0,lw1,lw2, ya0,ya1,ya2, h0v,h1v, wv[3], 0.f, tid); __syncthreads();
    level<64,  false>(buf[0], buf[1], lw0,lw1,lw2, ya0,ya1,ya2, h0v,h1v, wv[2], 0.f, tid); __syncthreads();
    level<128, true >(buf[1], buf[0], lw0,lw1,lw2, ya0,ya1,ya2, h0v,h1v, wv[1], wv[0], tid);

    // ---- Epilogue: fp32 GELU, two float4 stores per stored unit ----
    auto emit = [&](int g, h8 v) {
        float4 oa, ob;
        oa.x = gelu_f((float)v[0]); oa.y = gelu_f((float)v[1]);
        oa.z = gelu_f((float)v[2]); oa.w = gelu_f((float)v[3]);
        ob.x = gelu_f((float)v[4]); ob.y = gelu_f((float)v[5]);
        ob.z = gelu_f((float)v[6]); ob.w = gelu_f((float)v[7]);
        const long idx = row + (t0 + 8 * g);
        st4f(&out[idx], oa);
        st4f(&out[idx + 4], ob);
    };
    if (tid >= HALO_U) emit(tid,       ya0);   // slot0 in-tile part
    emit(tid + BLK,                    ya1);   // slot1 always in-tile
    if (tid < NU - 2 * BLK) emit(tid + 2 * BLK, ya2);   // real slot2 units only
}

}  // namespace

extern "C" void kernel_launch(void* const* d_in, const int* in_sizes, int n_in,
                              void* d_out, int out_size, void* d_ws, size_t ws_size,
                              hipStream_t stream)
{
    const float* x  = (const float*)d_in[0];
    const float* h0 = (const float*)d_in[1];
    const float* h1 = (const float*)d_in[2];
    const float* w  = (const float*)d_in[3];
    float* out = (float*)d_out;

    const int nblocks = (out_size / L_) * NT;   // B*C*NT = 4096
    cmrc_kernel<<<nblocks, BLK, 0, stream>>>(x, h0, h1, w, out);
}

// Round 8
// 45.565 us; speedup vs baseline: 12.4074x; 1.9830x over previous
//
#include <hip/hip_runtime.h>
#include <cmath>

namespace {

typedef _Float16 h8 __attribute__((ext_vector_type(8)));

constexpr int C_     = 64;
constexpr int L_     = 32768;
constexpr int TILE   = 4096;
constexpr int HALO   = 776;           // receptive field 765, rounded to unit-8
constexpr int NB     = TILE + HALO;   // 4872 halfs
constexpr int NU     = NB / 8;        // 609 h8 units
constexpr int HALO_U = HALO / 8;      // 97
constexpr int NT     = L_ / TILE;     // 8 tiles per row
constexpr int BLK    = 256;
constexpr int UMAX   = (NU + BLK - 1) / BLK;   // 3 unit-slots per thread (last partial)

__device__ __forceinline__ h8 ld8(const _Float16* p) { return *reinterpret_cast<const h8*>(p); }
__device__ __forceinline__ void st8(_Float16* p, h8 v) { *reinterpret_cast<h8*>(p) = v; }
__device__ __forceinline__ float4 ld4f(const float* p) { return *reinterpret_cast<const float4*>(p); }
__device__ __forceinline__ void st4f(float* p, float4 v) { *reinterpret_cast<float4*>(p) = v; }
__device__ __forceinline__ h8 sp8(_Float16 v) { return (h8){v,v,v,v,v,v,v,v}; }

template<int K>
__device__ __forceinline__ h8 shconc(h8 A, h8 B) {
    return __builtin_shufflevector(A, B, K, K+1, K+2, K+3, K+4, K+5, K+6, K+7);
}

// tanh-form GELU: v * sigmoid(1.5958*v + 0.07135*v^3); absmax-verified vs the
// erf form across four rounds (identical 0.0078125 overall absmax).
__device__ __forceinline__ float gelu_f(float v) {
    const float z = v * (1.5957691216057308f + 0.0713548162726f * v * v);
    const float e = __expf(-z);
    return v * __builtin_amdgcn_rcpf(1.0f + e);
}

// One level, dilation D. Each thread owns h8 units (8 consecutive elems).
// T3 = own unit (registers); T0..T2 = taps at p-3D, p-2D, p-D from LDS.
// Frontier recursion (verified): valid-start V: 0->8->16->32->56->104->200->392->776=HALO.
// STARTU = first unit whose reads stay >= previous V. Guards kept per-slot:
// they bound register live ranges (r4-r7 showed unguarded variants hoist 9
// loads -> 188 VGPR or forced spill).
template<int D, int STARTU, bool LAST>
__device__ __forceinline__ void level_pass(const _Float16* __restrict__ src,
                                           _Float16* __restrict__ dst,
                                           const float* h0f, const float* h1f,
                                           float wi, float w0,
                                           h8* lw, h8* yacc, int tid)
{
    _Float16 c1[4], c0[4];
#pragma unroll
    for (int t = 0; t < 4; ++t) {
        c1[t] = (_Float16)(wi * h1f[t]);
        c0[t] = (_Float16)(LAST ? w0 * h0f[t] : h0f[t]);
    }

#pragma unroll
    for (int u = 0; u < UMAX; ++u) {
        const int un = tid + u * BLK;
        if (un >= STARTU && un < NU) {
            const int p = 8 * un;
            const h8 T3 = lw[u];
            h8 T0, T1, T2;
            if constexpr (D == 1) {
                h8 Lv = ld8(&src[p - 8]);
                T0 = shconc<5>(Lv, T3);
                T1 = shconc<6>(Lv, T3);
                T2 = shconc<7>(Lv, T3);
            } else if constexpr (D == 2) {
                h8 Lv = ld8(&src[p - 8]);
                T0 = shconc<2>(Lv, T3);
                T1 = shconc<4>(Lv, T3);
                T2 = shconc<6>(Lv, T3);
            } else if constexpr (D == 4) {
                h8 Lv  = ld8(&src[p - 8]);
                h8 LL  = ld8(&src[p - 16]);
                T0 = shconc<4>(LL, Lv);
                T1 = Lv;
                T2 = shconc<4>(Lv, T3);
            } else {
                T0 = ld8(&src[p - 3 * D]);
                T1 = ld8(&src[p - 2 * D]);
                T2 = ld8(&src[p - D]);
            }
            if (un >= HALO_U) {   // y only matters inside the output tile
                yacc[u] += sp8(c1[0]) * T0 + sp8(c1[1]) * T1
                         + sp8(c1[2]) * T2 + sp8(c1[3]) * T3;
            }
            h8 nl = sp8(c0[0]) * T0 + sp8(c0[1]) * T1
                  + sp8(c0[2]) * T2 + sp8(c0[3]) * T3;
            if constexpr (LAST) {
                yacc[u] += nl;          // c0 already folded with w0
            } else {
                lw[u] = nl;
                st8(&dst[p], nl);
            }
        }
    }
}

// min-waves=8: VGPR cap 64. The GUARDED structure measured 28 VGPR at cap 73
// (r3) — 2.3x headroom. (The r5 spill at cap 64 was the unguarded variant.)
// LDS 2x9744B -> 8 blocks/CU -> 32-wave/CU HW ceiling.
__global__ __launch_bounds__(BLK, 8)
void cmrc_kernel(const float* __restrict__ x,
                 const float* __restrict__ h0,
                 const float* __restrict__ h1,
                 const float* __restrict__ w,
                 float* __restrict__ out)
{
    __shared__ alignas(16) _Float16 buf[2][NB];

    const int tid  = threadIdx.x;
    const int blk  = blockIdx.x;
    const int tile = blk % NT;
    const int bc   = blk / NT;            // b*C + c
    const int c    = bc % C_;
    const long row = (long)bc * L_;
    const int  t0  = tile * TILE - HALO;  // global pos of buffer p=0

    float h0v[4], h1v[4];
#pragma unroll
    for (int k = 0; k < 4; ++k) { h0v[k] = h0[c*4+k]; h1v[k] = h1[c*4+k]; }
    float wv[10];
#pragma unroll
    for (int i = 0; i < 10; ++i) wv[i] = w[c*10+i];

    h8 lw[UMAX];     // running low residual (own units, registers)
    h8 yacc[UMAX];   // packed y accumulator

    const _Float16 w9h = (_Float16)wv[9];

    // Stage x as fp16 (zeros left of t=0); init lw = x, y = w9*x.
#pragma unroll
    for (int u = 0; u < UMAX; ++u) {
        yacc[u] = sp8((_Float16)0.f);
        const int un = tid + u * BLK;
        if (un < NU) {
            const int p = 8 * un;
            const int t = t0 + p;
            float4 xa = make_float4(0.f, 0.f, 0.f, 0.f);
            float4 xb = make_float4(0.f, 0.f, 0.f, 0.f);
            if (t >= 0)     xa = ld4f(&x[row + t]);
            if (t + 4 >= 0) xb = ld4f(&x[row + t + 4]);
            h8 hv;
            hv[0] = (_Float16)xa.x; hv[1] = (_Float16)xa.y;
            hv[2] = (_Float16)xa.z; hv[3] = (_Float16)xa.w;
            hv[4] = (_Float16)xb.x; hv[5] = (_Float16)xb.y;
            hv[6] = (_Float16)xb.z; hv[7] = (_Float16)xb.w;
            st8(&buf[0][p], hv);
            lw[u] = hv;
            if (un >= HALO_U) yacc[u] = sp8(w9h) * hv;
        }
    }
    __syncthreads();

    level_pass<1,   1,  false>(buf[0], buf[1], h0v, h1v, wv[8], 0.f, lw, yacc, tid); __syncthreads();
    level_pass<2,   2,  false>(buf[1], buf[0], h0v, h1v, wv[7], 0.f, lw, yacc, tid); __syncthreads();
    level_pass<4,   4,  false>(buf[0], buf[1], h0v, h1v, wv[6], 0.f, lw, yacc, tid); __syncthreads();
    level_pass<8,   7,  false>(buf[1], buf[0], h0v, h1v, wv[5], 0.f, lw, yacc, tid); __syncthreads();
    level_pass<16,  13, false>(buf[0], buf[1], h0v, h1v, wv[4], 0.f, lw, yacc, tid); __syncthreads();
    level_pass<32,  25, false>(buf[1], buf[0], h0v, h1v, wv[3], 0.f, lw, yacc, tid); __syncthreads();
    level_pass<64,  49, false>(buf[0], buf[1], h0v, h1v, wv[2], 0.f, lw, yacc, tid); __syncthreads();
    level_pass<128, 97, true >(buf[1], buf[0], h0v, h1v, wv[1], wv[0], lw, yacc, tid);

    // Epilogue: unpack to fp32, GELU, two float4 stores per unit.
#pragma unroll
    for (int u = 0; u < UMAX; ++u) {
        const int un = tid + u * BLK;
        if (un >= HALO_U && un < NU) {
            const int p = 8 * un;
            const h8 v = yacc[u];
            float4 oa, ob;
            oa.x = gelu_f((float)v[0]); oa.y = gelu_f((float)v[1]);
            oa.z = gelu_f((float)v[2]); oa.w = gelu_f((float)v[3]);
            ob.x = gelu_f((float)v[4]); ob.y = gelu_f((float)v[5]);
            ob.z = gelu_f((float)v[6]); ob.w = gelu_f((float)v[7]);
            st4f(&out[row + t0 + p], oa);
            st4f(&out[row + t0 + p + 4], ob);
        }
    }
}

}  // namespace

extern "C" void kernel_launch(void* const* d_in, const int* in_sizes, int n_in,
                              void* d_out, int out_size, void* d_ws, size_t ws_size,
                              hipStream_t stream)
{
    const float* x  = (const float*)d_in[0];
    const float* h0 = (const float*)d_in[1];
    const float* h1 = (const float*)d_in[2];
    const float* w  = (const float*)d_in[3];
    float* out = (float*)d_out;

    const int nblocks = (out_size / L_) * NT;   // B*C*NT = 4096
    cmrc_kernel<<<nblocks, BLK, 0, stream>>>(x, h0, h1, w, out);
}